// Round 2
// baseline (29.403 us; speedup 1.0000x reference)
//
#include <hip/hip_runtime.h>

// CPAB 1D warp + linear resample, wave-autonomous version (no __syncthreads).
// x:     [B, LIN, C]  f32   (d_in[0])
// theta: [B, D]       f32   (d_in[1])
// basis: [2*NC, D]    f32   (d_in[2])
// out:   [B, OUTLEN, C] f32

#define NSTEPS 64
#define NC     32
#define DD     33      // nC + 1
#define LIN    2048
#define CCH    32
#define OUTLEN 2048
#define JPW    64      // j positions per wave
#define WPB    4       // waves per block
#define JPB    (JPW * WPB)   // 256

__global__ __launch_bounds__(256) void cpab_warp_kernel(
    const float* __restrict__ x,
    const float* __restrict__ theta,
    const float* __restrict__ basis,
    float* __restrict__ out)
{
    // wave-private LDS: same-wave write->read ordered by lgkmcnt, no barrier
    __shared__ float2 ctab[WPB][NC];    // (c1, c0) per cell: phi' = c1*phi + c0
    __shared__ float2 iw[WPB][JPW];     // (w, i0) per j

    const int t    = threadIdx.x;
    const int wave = t >> 6;
    const int lane = t & 63;
    const int blocksPerB = OUTLEN / JPB;            // 8
    const int b     = blockIdx.x / blocksPerB;
    const int jbase = (blockIdx.x % blocksPerB) * JPB + wave * JPW;

    const float dt = 1.0f / (float)NSTEPS;

    // Phase 0 (per wave): lane k computes A_k = basis[k,:] . theta[b,:]
    float acc = 0.0f;
    {
        const float* bs = basis + lane * DD;
        const float* th = theta + b * DD;
        #pragma unroll
        for (int d = 0; d < DD; ++d) acc = fmaf(bs[d], th[d], acc);
    }
    {
        // cell c: a = A[2c], b = A[2c+1]  ->  c1 = 1 + a*dt, c0 = b*dt
        int c = lane & (NC - 1);
        float a  = __shfl(acc, 2 * c);
        float bb = __shfl(acc, 2 * c + 1);
        if (lane < NC) ctab[wave][c] = make_float2(fmaf(a, dt, 1.0f), bb * dt);
    }

    // Phase 1 (per wave): integrate one trajectory per lane
    {
        const int j = jbase + lane;
        float phi = (float)j * (1.0f / (float)(OUTLEN - 1));
        const float2* ct = ctab[wave];
        #pragma unroll
        for (int s = 0; s < NSTEPS; ++s) {
            // truncation == floor after clamp-to-[0,31] (negatives clamp to 0)
            float f = fminf(fmaxf(phi * (float)NC, 0.0f), (float)(NC - 1)); // v_med3
            float2 cc = ct[(int)f];
            phi = fmaf(cc.x, phi, cc.y);
        }
        float p = fminf(fmaxf(phi, 0.0f), 1.0f) * (float)(LIN - 1);
        int i0 = min(max((int)p, 0), LIN - 2);   // p >= 0 so trunc == floor
        iw[wave][lane] = make_float2(p - (float)i0, (float)i0);
    }

    // Phase 2 (per wave): resample 64 j x 32 c as float4 (8 iters)
    const float4* xb = (const float4*)(x + (size_t)b * (LIN * CCH));
    float4* ob = (float4*)(out + ((size_t)b * OUTLEN + jbase) * CCH);
    const int c4  = lane & 7;        // float4 column within row (32 ch = 8 float4)
    const int jl0 = lane >> 3;       // 0..7
    #pragma unroll
    for (int it = 0; it < JPW / 8; ++it) {
        int jl = it * 8 + jl0;
        float2 f = iw[wave][jl];     // 8-lane broadcast per address
        int   i0 = (int)f.y;
        float w  = f.x;
        float4 g0 = xb[i0 * (CCH / 4) + c4];
        float4 g1 = xb[(i0 + 1) * (CCH / 4) + c4];
        float4 r;
        r.x = fmaf(w, g1.x - g0.x, g0.x);
        r.y = fmaf(w, g1.y - g0.y, g0.y);
        r.z = fmaf(w, g1.z - g0.z, g0.z);
        r.w = fmaf(w, g1.w - g0.w, g0.w);
        ob[jl * (CCH / 4) + c4] = r;
    }
}

extern "C" void kernel_launch(void* const* d_in, const int* in_sizes, int n_in,
                              void* d_out, int out_size, void* d_ws, size_t ws_size,
                              hipStream_t stream) {
    const float* x     = (const float*)d_in[0];
    const float* theta = (const float*)d_in[1];
    const float* basis = (const float*)d_in[2];
    float* out = (float*)d_out;

    const int B = in_sizes[1] / DD;                 // 256
    const int grid = B * (OUTLEN / JPB);            // 2048 blocks
    cpab_warp_kernel<<<grid, 256, 0, stream>>>(x, theta, basis, out);
}